// Round 9
// baseline (340.199 us; speedup 1.0000x reference)
//
#include <hip/hip_runtime.h>
#include <hip/hip_bf16.h>

typedef short bf16x8 __attribute__((ext_vector_type(8)));
typedef float f32x4 __attribute__((ext_vector_type(4)));

#define CCH 512
#define NPIX 4096
#define NB 4

__device__ inline unsigned short f2bf(float f) {
  union { __hip_bfloat16 h; unsigned short u; } cv;
  cv.h = __float2bfloat16(f);
  return cv.u;
}

#define GLD16(gp, lp) __builtin_amdgcn_global_load_lds( \
    (const __attribute__((address_space(1))) unsigned int*)(gp), \
    (__attribute__((address_space(3))) unsigned int*)(lp), 16, 0, 0)

// ---------------- weight fp32 -> bf16 cast ----------------
__global__ __launch_bounds__(256) void cast_weights_k(
    const float* __restrict__ w0, const float* __restrict__ w1,
    const float* __restrict__ w2, const float* __restrict__ w3,
    unsigned short* __restrict__ out) {
  int z = blockIdx.y;
  const float* src = (z == 0) ? w0 : (z == 1) ? w1 : (z == 2) ? w2 : w3;
  long i = (long)blockIdx.x * 256 + threadIdx.x;
  out[(long)z * CCH * CCH + i] = f2bf(src[i]);
}

// ---------------- concat bq,bk -> bqk[1024] ----------------
__global__ __launch_bounds__(256) void bias_concat_k(
    const float* __restrict__ bq, const float* __restrict__ bk,
    float* __restrict__ bqk) {
  int i = blockIdx.x * 256 + threadIdx.x;
  bqk[i] = (i < CCH) ? bq[i] : bk[i - CCH];
}

// ---------------- zero the softmax row-sum accumulator ----------------
__global__ __launch_bounds__(256) void zero_l_k(float* __restrict__ lsum) {
  int i = (blockIdx.x * 256 + threadIdx.x) * 4;
  *(float4*)(lsum + i) = make_float4(0.f, 0.f, 0.f, 0.f);
}

// ---------------- instance-norm stats: one block per (b,c) plane ----------------
__global__ __launch_bounds__(256) void stats_k(const float* __restrict__ x,
                                               float* __restrict__ stats) {
  long plane = blockIdx.x;
  const float4* p = (const float4*)(x + plane * NPIX);
  int t = threadIdx.x;
  float s = 0.f, q = 0.f;
  for (int c = 0; c < 4; c++) {
    float4 v = p[c * 256 + t];
    s += v.x + v.y + v.z + v.w;
    q += v.x * v.x + v.y * v.y + v.z * v.z + v.w * v.w;
  }
  for (int off = 32; off; off >>= 1) { s += __shfl_xor(s, off); q += __shfl_xor(q, off); }
  __shared__ float rs[4], rq[4];
  int w = t >> 6;
  if ((t & 63) == 0) { rs[w] = s; rq[w] = q; }
  __syncthreads();
  if (t == 0) {
    s = rs[0] + rs[1] + rs[2] + rs[3];
    q = rq[0] + rq[1] + rq[2] + rq[3];
    float mu = s * (1.f / NPIX);
    float var = q * (1.f / NPIX) - mu * mu;
    stats[2 * plane] = mu;
    stats[2 * plane + 1] = rsqrtf(var + 1e-5f);
  }
}

// ---------------- normalize + transpose: x[b][c][i] -> hnT[b][i][c] bf16 ----------------
__global__ __launch_bounds__(256) void norm_t_k(const float* __restrict__ x,
                                                const float* __restrict__ stats,
                                                unsigned short* __restrict__ hnT) {
  int b = blockIdx.z;
  int c0 = blockIdx.y * 32, i0 = blockIdx.x * 32;
  __shared__ float tile[32][33];
  int t = threadIdx.x;
  int il = t & 31, cl = t >> 5;  // cl in 0..7
  for (int r = 0; r < 4; r++) {
    int c = c0 + cl + r * 8;
    long pl = (long)b * CCH + c;
    float mu = stats[2 * pl], rsg = stats[2 * pl + 1];
    tile[cl + r * 8][il] = (x[pl * NPIX + i0 + il] - mu) * rsg;
  }
  __syncthreads();
  for (int r = 0; r < 4; r++) {
    int i = i0 + cl + r * 8;
    hnT[((long)b * NPIX + i) * CCH + c0 + il] = f2bf(tile[il][cl + r * 8]);
  }
}

// ---------------- generic bf16 gemm_bt: C[m][n] = A[m][k] * B[n][k] ----------------
// BM x 256 tile (BM = 128 or 256), BK=64, 512 threads = 8 waves in a 2(M)x4(N)
// grid, per-wave output (BM/2) x 64: MR = BM/32 m-frags x 4 n-frags of 16x16x32.
// global_load_lds dwordx4 staging, double-buffered LDS, counted-vmcnt pipeline
// (stage next tile, wait only current tile's loads, raw barrier pair; with the
// big tile the ~2000cy MFMA phase fully hides load latency).
// LDS XOR chunk-swizzle (T2, r6-proven 0-conflict): elem (row,e) at
// row*64 + ((e>>3)^(row&7))*8 + (e&7); pre-swizzled GLOBAL source col (linear
// gload_lds dest), same XOR on frag reads.
// OUTF32: 1 -> float C. BIASM: 0 none, 1 bias[m], 2 bias[n].
// EXPSUM: epilogue v=exp2(v) (scale carries log2e), atomicAdd row sums to lsum.
// ROWSCALE: epilogue v *= 1/lsum[z*NPIX+m].
template <int BM, int OUTF32, int BIASM, bool RESID, bool SCALE, bool EXPSUM, bool ROWSCALE>
__global__ __launch_bounds__(512) void gemm_bt_k(
    const unsigned short* __restrict__ A, const unsigned short* __restrict__ B,
    void* __restrict__ Cv, const float* __restrict__ bias,
    const float* __restrict__ resid, float* __restrict__ lsum,
    int K, int lda, int ldb, int ldc,
    long sA, long sB, long sC, float scale) {
  constexpr int BN = 256;
  constexpr int MR = BM / 32;        // m-frags per wave (4 or 8)
  constexpr int NR = 4;              // n-frags per wave
  constexpr int ALD = BM / 64;       // gload_lds per thread for A per K-step
  constexpr int BLD = BN / 64;       // = 4
  int z = blockIdx.z;
  A += z * sA;
  B += z * sB;
  const int n0 = blockIdx.x * BN, m0 = blockIdx.y * BM;
  const int t = threadIdx.x;         // 0..511
  const int lane = t & 63, w = t >> 6;
  const int wr = w >> 2, wc = w & 3; // 2 x 4 wave grid

  __shared__ __align__(16) unsigned short LA[2][BM * 64];
  __shared__ __align__(16) unsigned short LB[2][BN * 64];

  f32x4 acc[MR][NR] = {};

  // staging: load p covers rows p*64 + (t>>3); source chunk pre-swizzled.
  const int srow = t >> 3;                        // 0..63
  const int scol = (((t & 7) ^ (srow & 7)) * 8);  // swizzled source col
  const unsigned short* ga = A + (long)(m0 + srow) * lda + scol;
  const unsigned short* gb = B + (long)(n0 + srow) * ldb + scol;
  const long stpa = (long)64 * lda;
  const long stpb = (long)64 * ldb;

#define STAGE(bb, kt) do {                                                   \
    const unsigned short* gak = ga + (long)(kt) * 64;                        \
    const unsigned short* gbk = gb + (long)(kt) * 64;                        \
    char* la = (char*)&LA[bb][0] + t * 16;                                   \
    char* lb = (char*)&LB[bb][0] + t * 16;                                   \
    _Pragma("unroll")                                                        \
    for (int p = 0; p < ALD; p++) GLD16(gak + p * stpa, la + p * 8192);      \
    _Pragma("unroll")                                                        \
    for (int p = 0; p < BLD; p++) GLD16(gbk + p * stpb, lb + p * 8192);      \
  } while (0)

  const int fr = lane & 15, fq = lane >> 4;
  const int chx = fr & 7;  // read-side XOR key (row&7 == fr&7)
  const int rAbase = (wr * (BM / 2) + fr) * 64;
  const int rBbase = (wc * 64 + fr) * 64;

  const int nkt = K >> 6;
  STAGE(0, 0);
  int cur = 0;
  for (int kt = 0; kt < nkt; kt++) {
    if (kt + 1 < nkt) {
      STAGE(cur ^ 1, kt + 1);  // prefetch next tile (stays in flight)
      if (BM == 256)
        asm volatile("s_waitcnt vmcnt(8)" ::: "memory");
      else
        asm volatile("s_waitcnt vmcnt(6)" ::: "memory");
    } else {
      asm volatile("s_waitcnt vmcnt(0)" ::: "memory");
    }
    __builtin_amdgcn_s_barrier();  // all waves: current tile resident
    const unsigned short* la_ = &LA[cur][0];
    const unsigned short* lb_ = &LB[cur][0];
    __builtin_amdgcn_s_setprio(1);
    bf16x8 bfr[NR][2];
#pragma unroll
    for (int n = 0; n < NR; n++) {
      bfr[n][0] = *(const bf16x8*)(lb_ + rBbase + n * 1024 + (fq ^ chx) * 8);
      bfr[n][1] = *(const bf16x8*)(lb_ + rBbase + n * 1024 + ((fq + 4) ^ chx) * 8);
    }
#pragma unroll
    for (int m = 0; m < MR; m++) {
      bf16x8 a0 = *(const bf16x8*)(la_ + rAbase + m * 1024 + (fq ^ chx) * 8);
      bf16x8 a1 = *(const bf16x8*)(la_ + rAbase + m * 1024 + ((fq + 4) ^ chx) * 8);
#pragma unroll
      for (int n = 0; n < NR; n++) {
        acc[m][n] = __builtin_amdgcn_mfma_f32_16x16x32_bf16(a0, bfr[n][0], acc[m][n], 0, 0, 0);
        acc[m][n] = __builtin_amdgcn_mfma_f32_16x16x32_bf16(a1, bfr[n][1], acc[m][n], 0, 0, 0);
      }
    }
    __builtin_amdgcn_s_setprio(0);
    __builtin_amdgcn_s_barrier();  // reads of LDS[cur] done before next overwrite
    cur ^= 1;
  }
#undef STAGE

  // epilogue: C/D layout col = lane&15, row = (lane>>4)*4 + r  (m89-verified)
  if (OUTF32) {
    float* Cf = (float*)Cv;
    for (int i = 0; i < MR; i++) {
      int mg = m0 + wr * (BM / 2) + i * 16 + fq * 4;
      for (int j = 0; j < NR; j++) {
        int ng = n0 + wc * 64 + j * 16 + fr;
        for (int r = 0; r < 4; r++) {
          float v = acc[i][j][r];
          if (SCALE) v *= scale;
          int m = mg + r;
          if (BIASM == 1) v += bias[m];
          else if (BIASM == 2) v += bias[ng];
          long off = z * sC + (long)m * ldc + ng;
          if (RESID) v += resid[off];
          Cf[off] = v;
        }
      }
    }
  } else {
    float linv[MR][4];
    if (ROWSCALE) {
      for (int i = 0; i < MR; i++)
        for (int r = 0; r < 4; r++)
          linv[i][r] = 1.f / lsum[z * NPIX + m0 + wr * (BM / 2) + i * 16 + fq * 4 + r];
    }
    float rsum[MR][4];
    if (EXPSUM) {
      for (int i = 0; i < MR; i++)
        for (int r = 0; r < 4; r++) rsum[i][r] = 0.f;
    }
    unsigned short* Cb = (unsigned short*)Cv;
    for (int i = 0; i < MR; i++) {
      int mg = m0 + wr * (BM / 2) + i * 16 + fq * 4;
      for (int j = 0; j < NR; j++) {
        int ng = n0 + wc * 64 + j * 16 + fr;
        for (int r = 0; r < 4; r++) {
          float v = acc[i][j][r];
          if (SCALE) v *= scale;
          if (BIASM == 1) v += bias[mg + r];
          else if (BIASM == 2) v += bias[ng];
          if (EXPSUM) { v = exp2f(v); rsum[i][r] += v; }  // scale carries log2e
          if (ROWSCALE) v *= linv[i][r];
          Cb[z * sC + (long)(mg + r) * ldc + ng] = f2bf(v);
        }
      }
    }
    if (EXPSUM) {
      for (int i = 0; i < MR; i++)
        for (int r = 0; r < 4; r++) {
          float s = rsum[i][r];
          s += __shfl_xor(s, 1);
          s += __shfl_xor(s, 2);
          s += __shfl_xor(s, 4);
          s += __shfl_xor(s, 8);
          if (fr == 0)
            atomicAdd(&lsum[z * NPIX + m0 + wr * (BM / 2) + i * 16 + fq * 4 + r], s);
        }
    }
  }
}

extern "C" void kernel_launch(void* const* d_in, const int* in_sizes, int n_in,
                              void* d_out, int out_size, void* d_ws, size_t ws_size,
                              hipStream_t stream) {
  const float* x  = (const float*)d_in[0];
  const float* wq = (const float*)d_in[1];
  const float* bq = (const float*)d_in[2];
  const float* wk = (const float*)d_in[3];
  const float* bk = (const float*)d_in[4];
  const float* wv = (const float*)d_in[5];
  const float* bv = (const float*)d_in[6];
  const float* wp = (const float*)d_in[7];
  const float* bp = (const float*)d_in[8];

  char* ws = (char*)d_ws;
  const long SLAB = (long)NPIX * CCH;     // 2M elems: one batch of hnT/V/Ot
  const long SLAB2 = (long)NPIX * 1024;   // 4M elems: one batch of QKt
  const long SLABP = (long)NPIX * NPIX;   // 16.8M elems: one batch of E

  float* stats = (float*)ws;                                  // 16 KB
  float* bqk = (float*)(ws + (32l << 10));                    // 4 KB
  float* lsum = (float*)(ws + (64l << 10));                   // 64 KB [b][i]
  unsigned short* wbf = (unsigned short*)(ws + (192l << 10)); // 2 MB
  unsigned short* hnT = (unsigned short*)(ws + (192l << 10) + (1l << 21));
  unsigned short* QKt = hnT + 4 * SLAB;   // [b][i][0:512 Q | 512:1024 K], 32 MB
  unsigned short* V   = QKt + 4 * SLAB2;  // [b][o][j], 16 MB
  unsigned short* Ot  = V + 4 * SLAB;     // [b][i][c], 16 MB
  unsigned short* S4  = Ot + 4 * SLAB;    // [b][i][j] bf16 E=exp(S), 128 MB
  // total: ~210 MB

  unsigned short* wv_bf = wbf + 2 * 262144;
  unsigned short* wp_bf = wbf + 3 * 262144;

  cast_weights_k<<<dim3(1024, 4, 1), 256, 0, stream>>>(wq, wk, wv, wp, wbf);
  bias_concat_k<<<dim3(4, 1, 1), 256, 0, stream>>>(bq, bk, bqk);
  zero_l_k<<<dim3(16, 1, 1), 256, 0, stream>>>(lsum);
  stats_k<<<dim3(NB * CCH, 1, 1), 256, 0, stream>>>(x, stats);
  norm_t_k<<<dim3(128, 16, 4), 256, 0, stream>>>(x, stats, hnT);

  // QKt[b][i][n] = hnT[b] . [wq;wk]^T + bqk   (n in 0..1023)
  gemm_bt_k<256, 0, 2, false, false, false, false><<<dim3(4, 16, 4), 512, 0, stream>>>(
      hnT, wbf, QKt, bqk, nullptr, nullptr, 512, 512, 512, 1024, SLAB, 0, SLAB2, 1.f);
  // V[b][o][j] = Wv . hnT[b]^T + bv (bias over rows)
  gemm_bt_k<128, 0, 1, false, false, false, false><<<dim3(16, 4, 4), 512, 0, stream>>>(
      wv_bf, hnT, V, bv, nullptr, nullptr, 512, 512, 512, 4096, 0, SLAB, SLAB, 1.f);

  // scale = (1/sqrt(512)) * log2(e): E = exp2(S') == exp(S)
  const float isc2 = 0.06375871387551278f;
  // E[b][i][j] = exp(Q[b].K[b]^T / sqrt(C)) bf16; lsum[b][i] = sum_j E
  gemm_bt_k<256, 0, 0, false, true, true, false><<<dim3(16, 16, 4), 512, 0, stream>>>(
      QKt, QKt + 512, S4, nullptr, nullptr, lsum, 512, 1024, 1024, 4096,
      SLAB2, SLAB2, SLABP, isc2);
  // Ot[b][i][c] = (E[b] . V[b]^T) / lsum[b][i]
  gemm_bt_k<256, 0, 0, false, false, false, true><<<dim3(2, 16, 4), 512, 0, stream>>>(
      S4, V, Ot, nullptr, nullptr, lsum, 4096, 4096, 4096, 512, SLABP, SLAB, SLAB, 1.f);
  // out[b][o][i] = x + Wp . Ot[b]^T + bp
  gemm_bt_k<128, 1, 1, true, false, false, false><<<dim3(16, 4, 4), 512, 0, stream>>>(
      wp_bf, Ot, d_out, bp, x, nullptr, 512, 512, 512, 4096, 0, SLAB, SLAB, 1.f);
}

// Round 10
// 307.439 us; speedup vs baseline: 1.1066x; 1.1066x over previous
//
#include <hip/hip_runtime.h>
#include <hip/hip_bf16.h>

typedef short bf16x8 __attribute__((ext_vector_type(8)));
typedef float f32x4 __attribute__((ext_vector_type(4)));

#define CCH 512
#define NPIX 4096
#define NB 4

__device__ inline unsigned short f2bf(float f) {
  union { __hip_bfloat16 h; unsigned short u; } cv;
  cv.h = __float2bfloat16(f);
  return cv.u;
}

#define GLD16(gp, lp) __builtin_amdgcn_global_load_lds( \
    (const __attribute__((address_space(1))) unsigned int*)(gp), \
    (__attribute__((address_space(3))) unsigned int*)(lp), 16, 0, 0)

// ---------------- weight fp32 -> bf16 cast ----------------
__global__ __launch_bounds__(256) void cast_weights_k(
    const float* __restrict__ w0, const float* __restrict__ w1,
    const float* __restrict__ w2, const float* __restrict__ w3,
    unsigned short* __restrict__ out) {
  int z = blockIdx.y;
  const float* src = (z == 0) ? w0 : (z == 1) ? w1 : (z == 2) ? w2 : w3;
  long i = (long)blockIdx.x * 256 + threadIdx.x;
  out[(long)z * CCH * CCH + i] = f2bf(src[i]);
}

// ---------------- concat bq,bk -> bqk[1024] ----------------
__global__ __launch_bounds__(256) void bias_concat_k(
    const float* __restrict__ bq, const float* __restrict__ bk,
    float* __restrict__ bqk) {
  int i = blockIdx.x * 256 + threadIdx.x;
  bqk[i] = (i < CCH) ? bq[i] : bk[i - CCH];
}

// ---------------- zero the softmax row-sum accumulator ----------------
__global__ __launch_bounds__(256) void zero_l_k(float* __restrict__ lsum) {
  int i = (blockIdx.x * 256 + threadIdx.x) * 4;
  *(float4*)(lsum + i) = make_float4(0.f, 0.f, 0.f, 0.f);
}

// ---------------- instance-norm stats: one block per (b,c) plane ----------------
__global__ __launch_bounds__(256) void stats_k(const float* __restrict__ x,
                                               float* __restrict__ stats) {
  long plane = blockIdx.x;
  const float4* p = (const float4*)(x + plane * NPIX);
  int t = threadIdx.x;
  float s = 0.f, q = 0.f;
  for (int c = 0; c < 4; c++) {
    float4 v = p[c * 256 + t];
    s += v.x + v.y + v.z + v.w;
    q += v.x * v.x + v.y * v.y + v.z * v.z + v.w * v.w;
  }
  for (int off = 32; off; off >>= 1) { s += __shfl_xor(s, off); q += __shfl_xor(q, off); }
  __shared__ float rs[4], rq[4];
  int w = t >> 6;
  if ((t & 63) == 0) { rs[w] = s; rq[w] = q; }
  __syncthreads();
  if (t == 0) {
    s = rs[0] + rs[1] + rs[2] + rs[3];
    q = rq[0] + rq[1] + rq[2] + rq[3];
    float mu = s * (1.f / NPIX);
    float var = q * (1.f / NPIX) - mu * mu;
    stats[2 * plane] = mu;
    stats[2 * plane + 1] = rsqrtf(var + 1e-5f);
  }
}

// ---------------- normalize + transpose: x[b][c][i] -> hnT[b][i][c] bf16 ----------------
__global__ __launch_bounds__(256) void norm_t_k(const float* __restrict__ x,
                                                const float* __restrict__ stats,
                                                unsigned short* __restrict__ hnT) {
  int b = blockIdx.z;
  int c0 = blockIdx.y * 32, i0 = blockIdx.x * 32;
  __shared__ float tile[32][33];
  int t = threadIdx.x;
  int il = t & 31, cl = t >> 5;  // cl in 0..7
  for (int r = 0; r < 4; r++) {
    int c = c0 + cl + r * 8;
    long pl = (long)b * CCH + c;
    float mu = stats[2 * pl], rsg = stats[2 * pl + 1];
    tile[cl + r * 8][il] = (x[pl * NPIX + i0 + il] - mu) * rsg;
  }
  __syncthreads();
  for (int r = 0; r < 4; r++) {
    int i = i0 + cl + r * 8;
    hnT[((long)b * NPIX + i) * CCH + c0 + il] = f2bf(tile[il][cl + r * 8]);
  }
}

// ---------------- generic bf16 gemm_bt: C[m][n] = A[m][k] * B[n][k] ----------------
// r6-proven core (best: 315us): 128x128 tile, BK=64, global_load_lds dwordx4,
// single-buffered LDS, 2x __syncthreads per K-step, LDS XOR chunk-swizzle
// (0 bank conflicts): elem (row,e) at row*64 + ((e>>3)^(row&7))*8 + (e&7);
// pre-swizzled GLOBAL source col (linear gload_lds dest), XOR on frag reads.
// NEW: bijective 2D XCD-chunk swizzle (T1/m204): each XCD owns a contiguous
// (x,y) region of the grid -> operand slabs localized per-XCD L2 instead of
// replicated 8x. XCDX = XCD-grid columns (0 = no swizzle). Requires
// gridDim.x % XCDX == 0 and (gridDim.y * XCDX) % 8 == 0 and N % 8 == 0.
// OUTF32: 1 -> float C. BIASM: 0 none, 1 bias[m], 2 bias[n].
// EXPSUM: epilogue v=exp2(v) (scale carries log2e), atomicAdd row sums to lsum.
// ROWSCALE: epilogue v *= 1/lsum[z*NPIX+m].
template <int XCDX, int OUTF32, int BIASM, bool RESID, bool SCALE, bool EXPSUM, bool ROWSCALE>
__global__ __launch_bounds__(256) void gemm_bt_k(
    const unsigned short* __restrict__ A, const unsigned short* __restrict__ B,
    void* __restrict__ Cv, const float* __restrict__ bias,
    const float* __restrict__ resid, float* __restrict__ lsum,
    int K, int lda, int ldb, int ldc,
    long sA, long sB, long sC, float scale) {
  int z = blockIdx.z;
  A += z * sA;
  B += z * sB;

  int bx = blockIdx.x, by = blockIdx.y;
  if (XCDX > 0) {
    // slot -> XCD model: xcd = slot % 8 (z stride is N, N%8==0 -> phase stable)
    int s = blockIdx.x + gridDim.x * blockIdx.y;
    int xcd = s & 7, idx = s >> 3;
    int rw = gridDim.x / XCDX;            // region width  (x-tiles per XCD)
    int rh = (gridDim.y * XCDX) >> 3;     // region height (y-tiles per XCD)
    int rx0 = (xcd % XCDX) * rw, ry0 = (xcd / XCDX) * rh;
    bx = rx0 + idx % rw;
    by = ry0 + idx / rw;
  }
  const int n0 = bx * 128, m0 = by * 128;

  const int t = threadIdx.x;
  const int lane = t & 63, w = t >> 6;
  const int wr = w >> 1, wc = w & 1;

  __shared__ __align__(16) unsigned short As[128 * 64];  // 16 KB, [row][64] swizzled
  __shared__ __align__(16) unsigned short Bs[128 * 64];  // 16 KB

  f32x4 acc[4][4] = {};

  // staging: instr p covers rows p*32 + (t>>3); source chunk pre-swizzled.
  const int srow = t >> 3;                        // 0..31
  const int scol = (((t & 7) ^ (srow & 7)) * 8);  // swizzled source col
  const unsigned short* ga = A + (long)(m0 + srow) * lda + scol;
  const unsigned short* gb = B + (long)(n0 + srow) * ldb + scol;
  char* lA = (char*)As + t * 16;
  char* lB = (char*)Bs + t * 16;
  const long stpa = (long)32 * lda;
  const long stpb = (long)32 * ldb;

  const int fr = lane & 15, fq = lane >> 4;
  const int chx = fr & 7;  // read-side XOR key (row&7 == fr&7)
  const unsigned short* rA = As + (wr * 64 + fr) * 64;
  const unsigned short* rB = Bs + (wc * 64 + fr) * 64;

  const int nkt = K >> 6;
  for (int kt = 0; kt < nkt; kt++) {
    const unsigned short* gak = ga + (long)kt * 64;
    const unsigned short* gbk = gb + (long)kt * 64;
    GLD16(gak, lA);
    GLD16(gak + stpa, lA + 4096);
    GLD16(gak + 2 * stpa, lA + 8192);
    GLD16(gak + 3 * stpa, lA + 12288);
    GLD16(gbk, lB);
    GLD16(gbk + stpb, lB + 4096);
    GLD16(gbk + 2 * stpb, lB + 8192);
    GLD16(gbk + 3 * stpb, lB + 12288);
    __syncthreads();
    for (int kk = 0; kk < 2; kk++) {
      const int offA = ((fq + kk * 4) ^ chx) * 8;  // swizzled chunk offset
      bf16x8 af[4], bfr[4];
      for (int i = 0; i < 4; i++) af[i] = *(const bf16x8*)(rA + i * 1024 + offA);
      for (int i = 0; i < 4; i++) bfr[i] = *(const bf16x8*)(rB + i * 1024 + offA);
      for (int i = 0; i < 4; i++)
        for (int j = 0; j < 4; j++)
          acc[i][j] = __builtin_amdgcn_mfma_f32_16x16x32_bf16(af[i], bfr[j], acc[i][j], 0, 0, 0);
    }
    __syncthreads();
  }

  // epilogue: C/D layout col = lane&15, row = (lane>>4)*4 + r  (m89-verified)
  if (OUTF32) {
    float* Cf = (float*)Cv;
    for (int i = 0; i < 4; i++) {
      int mg = m0 + wr * 64 + i * 16 + fq * 4;
      for (int j = 0; j < 4; j++) {
        int ng = n0 + wc * 64 + j * 16 + fr;
        for (int r = 0; r < 4; r++) {
          float v = acc[i][j][r];
          if (SCALE) v *= scale;
          int m = mg + r;
          if (BIASM == 1) v += bias[m];
          else if (BIASM == 2) v += bias[ng];
          long off = z * sC + (long)m * ldc + ng;
          if (RESID) v += resid[off];
          Cf[off] = v;
        }
      }
    }
  } else {
    float linv[4][4];
    if (ROWSCALE) {
      for (int i = 0; i < 4; i++)
        for (int r = 0; r < 4; r++)
          linv[i][r] = 1.f / lsum[z * NPIX + m0 + wr * 64 + i * 16 + fq * 4 + r];
    }
    float rsum[4][4];
    if (EXPSUM) {
      for (int i = 0; i < 4; i++)
        for (int r = 0; r < 4; r++) rsum[i][r] = 0.f;
    }
    unsigned short* Cb = (unsigned short*)Cv;
    for (int i = 0; i < 4; i++) {
      int mg = m0 + wr * 64 + i * 16 + fq * 4;
      for (int j = 0; j < 4; j++) {
        int ng = n0 + wc * 64 + j * 16 + fr;
        for (int r = 0; r < 4; r++) {
          float v = acc[i][j][r];
          if (SCALE) v *= scale;
          if (BIASM == 1) v += bias[mg + r];
          else if (BIASM == 2) v += bias[ng];
          if (EXPSUM) { v = exp2f(v); rsum[i][r] += v; }  // scale carries log2e
          if (ROWSCALE) v *= linv[i][r];
          Cb[z * sC + (long)(mg + r) * ldc + ng] = f2bf(v);
        }
      }
    }
    if (EXPSUM) {
      for (int i = 0; i < 4; i++)
        for (int r = 0; r < 4; r++) {
          float s = rsum[i][r];
          s += __shfl_xor(s, 1);
          s += __shfl_xor(s, 2);
          s += __shfl_xor(s, 4);
          s += __shfl_xor(s, 8);
          if (fr == 0)
            atomicAdd(&lsum[z * NPIX + m0 + wr * 64 + i * 16 + fq * 4 + r], s);
        }
    }
  }
}

extern "C" void kernel_launch(void* const* d_in, const int* in_sizes, int n_in,
                              void* d_out, int out_size, void* d_ws, size_t ws_size,
                              hipStream_t stream) {
  const float* x  = (const float*)d_in[0];
  const float* wq = (const float*)d_in[1];
  const float* bq = (const float*)d_in[2];
  const float* wk = (const float*)d_in[3];
  const float* bk = (const float*)d_in[4];
  const float* wv = (const float*)d_in[5];
  const float* bv = (const float*)d_in[6];
  const float* wp = (const float*)d_in[7];
  const float* bp = (const float*)d_in[8];

  char* ws = (char*)d_ws;
  const long SLAB = (long)NPIX * CCH;     // 2M elems: one batch of hnT/V/Ot
  const long SLAB2 = (long)NPIX * 1024;   // 4M elems: one batch of QKt
  const long SLABP = (long)NPIX * NPIX;   // 16.8M elems: one batch of E

  float* stats = (float*)ws;                                  // 16 KB
  float* bqk = (float*)(ws + (32l << 10));                    // 4 KB
  float* lsum = (float*)(ws + (64l << 10));                   // 64 KB [b][i]
  unsigned short* wbf = (unsigned short*)(ws + (192l << 10)); // 2 MB
  unsigned short* hnT = (unsigned short*)(ws + (192l << 10) + (1l << 21));
  unsigned short* QKt = hnT + 4 * SLAB;   // [b][i][0:512 Q | 512:1024 K], 32 MB
  unsigned short* V   = QKt + 4 * SLAB2;  // [b][o][j], 16 MB
  unsigned short* Ot  = V + 4 * SLAB;     // [b][i][c], 16 MB
  unsigned short* S4  = Ot + 4 * SLAB;    // [b][i][j] bf16 E=exp(S), 128 MB
  // total: ~210 MB

  unsigned short* wv_bf = wbf + 2 * 262144;
  unsigned short* wp_bf = wbf + 3 * 262144;

  cast_weights_k<<<dim3(1024, 4, 1), 256, 0, stream>>>(wq, wk, wv, wp, wbf);
  bias_concat_k<<<dim3(4, 1, 1), 256, 0, stream>>>(bq, bk, bqk);
  zero_l_k<<<dim3(16, 1, 1), 256, 0, stream>>>(lsum);
  stats_k<<<dim3(NB * CCH, 1, 1), 256, 0, stream>>>(x, stats);
  norm_t_k<<<dim3(128, 16, 4), 256, 0, stream>>>(x, stats, hnT);

  // QKt[b][i][n] = hnT[b] . [wq;wk]^T + bqk  — XCD grid 1x8 over y (hnT slabs local)
  gemm_bt_k<1, 0, 2, false, false, false, false><<<dim3(8, 32, 4), 256, 0, stream>>>(
      hnT, wbf, QKt, bqk, nullptr, nullptr, 512, 512, 512, 1024, SLAB, 0, SLAB2, 1.f);
  // V[b][o][j] = Wv . hnT[b]^T + bv — XCD grid 2x4 (hnT x-slabs local)
  gemm_bt_k<2, 0, 1, false, false, false, false><<<dim3(32, 4, 4), 256, 0, stream>>>(
      wv_bf, hnT, V, bv, nullptr, nullptr, 512, 512, 512, 4096, 0, SLAB, SLAB, 1.f);

  // scale = (1/sqrt(512)) * log2(e): E = exp2(S') == exp(S)
  const float isc2 = 0.06375871387551278f;
  // E[b][i][j] = exp(Q[b].K[b]^T / sqrt(C)) bf16 — XCD grid 2x4 (Q 4x-dedup, K 2x)
  gemm_bt_k<2, 0, 0, false, true, true, false><<<dim3(32, 32, 4), 256, 0, stream>>>(
      QKt, QKt + 512, S4, nullptr, nullptr, lsum, 512, 1024, 1024, 4096,
      SLAB2, SLAB2, SLABP, isc2);
  // Ot[b][i][c] = (E[b] . V[b]^T) / lsum[b][i] — XCD grid 1x8 (E slabs local)
  gemm_bt_k<1, 0, 0, false, false, false, true><<<dim3(4, 32, 4), 256, 0, stream>>>(
      S4, V, Ot, nullptr, nullptr, lsum, 4096, 4096, 4096, 512, SLABP, SLAB, SLAB, 1.f);
  // out[b][o][i] = x + Wp . Ot[b]^T + bp — XCD grid 2x4 (Ot x-slabs local)
  gemm_bt_k<2, 1, 1, true, false, false, false><<<dim3(32, 4, 4), 256, 0, stream>>>(
      wp_bf, Ot, d_out, bp, x, nullptr, 512, 512, 512, 4096, 0, SLAB, SLAB, 1.f);
}

// Round 11
// 301.134 us; speedup vs baseline: 1.1297x; 1.0209x over previous
//
#include <hip/hip_runtime.h>
#include <hip/hip_bf16.h>

typedef short bf16x8 __attribute__((ext_vector_type(8)));
typedef float f32x4 __attribute__((ext_vector_type(4)));

#define CCH 512
#define NPIX 4096
#define NB 4

__device__ inline unsigned short f2bf(float f) {
  union { __hip_bfloat16 h; unsigned short u; } cv;
  cv.h = __float2bfloat16(f);
  return cv.u;
}

#define GLD16(gp, lp) __builtin_amdgcn_global_load_lds( \
    (const __attribute__((address_space(1))) unsigned int*)(gp), \
    (__attribute__((address_space(3))) unsigned int*)(lp), 16, 0, 0)

// ---------------- weight fp32 -> bf16 cast ----------------
__global__ __launch_bounds__(256) void cast_weights_k(
    const float* __restrict__ w0, const float* __restrict__ w1,
    const float* __restrict__ w2, const float* __restrict__ w3,
    unsigned short* __restrict__ out) {
  int z = blockIdx.y;
  const float* src = (z == 0) ? w0 : (z == 1) ? w1 : (z == 2) ? w2 : w3;
  long i = (long)blockIdx.x * 256 + threadIdx.x;
  out[(long)z * CCH * CCH + i] = f2bf(src[i]);
}

// ---------------- concat bq,bk -> bqk[1024] ----------------
__global__ __launch_bounds__(256) void bias_concat_k(
    const float* __restrict__ bq, const float* __restrict__ bk,
    float* __restrict__ bqk) {
  int i = blockIdx.x * 256 + threadIdx.x;
  bqk[i] = (i < CCH) ? bq[i] : bk[i - CCH];
}

// ---------------- zero the softmax row-sum accumulator ----------------
__global__ __launch_bounds__(256) void zero_l_k(float* __restrict__ lsum) {
  int i = (blockIdx.x * 256 + threadIdx.x) * 4;
  *(float4*)(lsum + i) = make_float4(0.f, 0.f, 0.f, 0.f);
}

// ---------------- instance-norm stats: one block per (b,c) plane ----------------
__global__ __launch_bounds__(256) void stats_k(const float* __restrict__ x,
                                               float* __restrict__ stats) {
  long plane = blockIdx.x;
  const float4* p = (const float4*)(x + plane * NPIX);
  int t = threadIdx.x;
  float s = 0.f, q = 0.f;
  for (int c = 0; c < 4; c++) {
    float4 v = p[c * 256 + t];
    s += v.x + v.y + v.z + v.w;
    q += v.x * v.x + v.y * v.y + v.z * v.z + v.w * v.w;
  }
  for (int off = 32; off; off >>= 1) { s += __shfl_xor(s, off); q += __shfl_xor(q, off); }
  __shared__ float rs[4], rq[4];
  int w = t >> 6;
  if ((t & 63) == 0) { rs[w] = s; rq[w] = q; }
  __syncthreads();
  if (t == 0) {
    s = rs[0] + rs[1] + rs[2] + rs[3];
    q = rq[0] + rq[1] + rq[2] + rq[3];
    float mu = s * (1.f / NPIX);
    float var = q * (1.f / NPIX) - mu * mu;
    stats[2 * plane] = mu;
    stats[2 * plane + 1] = rsqrtf(var + 1e-5f);
  }
}

// ---------------- normalize + transpose: x[b][c][i] -> hnT[b][i][c] bf16 ----------------
__global__ __launch_bounds__(256) void norm_t_k(const float* __restrict__ x,
                                                const float* __restrict__ stats,
                                                unsigned short* __restrict__ hnT) {
  int b = blockIdx.z;
  int c0 = blockIdx.y * 32, i0 = blockIdx.x * 32;
  __shared__ float tile[32][33];
  int t = threadIdx.x;
  int il = t & 31, cl = t >> 5;  // cl in 0..7
  for (int r = 0; r < 4; r++) {
    int c = c0 + cl + r * 8;
    long pl = (long)b * CCH + c;
    float mu = stats[2 * pl], rsg = stats[2 * pl + 1];
    tile[cl + r * 8][il] = (x[pl * NPIX + i0 + il] - mu) * rsg;
  }
  __syncthreads();
  for (int r = 0; r < 4; r++) {
    int i = i0 + cl + r * 8;
    hnT[((long)b * NPIX + i) * CCH + c0 + il] = f2bf(tile[il][cl + r * 8]);
  }
}

// ================= 8-phase 256x256 S-kernel =================
// E[b][i][j] = exp2(scale * Q.K^T), lsum[b][i] += row sums. K=512 fixed.
// 8 waves (wr=w>>2 in 0..1, wc=w&3 in 0..3); STRIDED frags: m-frag j at rows
// j*32+wr*16 (+fr), n-frag j at cols j*64+wc*16 (+fr) -> phase quadrant (qm,qn)
// touches exactly A-half qm and B-half qn. dbuf slots at K-tile granularity;
// per phase: stage ONE half-tile (2 gload_lds) into the slot freed >=4 phases
// ago; counted vmcnt(4)/vmcnt(2) at group phases 0/1 only (never 0 mid-loop).
// XOR chunk-swizzle as r6 (0 bank conflicts).
#define SH(sl, ha, h, kt) do {                                               \
    const unsigned short* g_ = ((ha) ? gB : gA) + (long)(kt) * 64 +          \
                               (long)(2 * (h)) * 65536;                      \
    char* l_ = (char*)LDSu + (sl) * 65536 + (ha) * 32768 + (2 * (h)) * 8192  \
               + t * 16;                                                     \
    GLD16(g_, l_);                                                           \
    GLD16(g_ + 65536, l_ + 8192);                                            \
  } while (0)

#define PH(sl, qm, qn, WN, SSTMT) do {                                       \
    if ((WN) == 4) asm volatile("s_waitcnt vmcnt(4)" ::: "memory");          \
    else if ((WN) == 2) asm volatile("s_waitcnt vmcnt(2)" ::: "memory");     \
    else if ((WN) == 0) asm volatile("s_waitcnt vmcnt(0)" ::: "memory");     \
    __builtin_amdgcn_s_barrier();                                            \
    __builtin_amdgcn_sched_barrier(0);                                       \
    SSTMT;                                                                   \
    const unsigned short* sa_ = LDSu + (sl) * 32768;                         \
    const unsigned short* sb_ = sa_ + 16384;                                 \
    bf16x8 a_[4][2], b_[2][2];                                               \
    _Pragma("unroll") for (int mm = 0; mm < 4; mm++) {                       \
      int row = ((qm) * 4 + mm) * 32 + wr * 16 + fr;                         \
      a_[mm][0] = *(const bf16x8*)(sa_ + row * 64 + o0_);                    \
      a_[mm][1] = *(const bf16x8*)(sa_ + row * 64 + o1_);                    \
    }                                                                        \
    _Pragma("unroll") for (int nn = 0; nn < 2; nn++) {                       \
      int row = ((qn) * 2 + nn) * 64 + wc * 16 + fr;                         \
      b_[nn][0] = *(const bf16x8*)(sb_ + row * 64 + o0_);                    \
      b_[nn][1] = *(const bf16x8*)(sb_ + row * 64 + o1_);                    \
    }                                                                        \
    asm volatile("s_waitcnt lgkmcnt(0)" ::: "memory");                       \
    __builtin_amdgcn_sched_barrier(0);                                       \
    __builtin_amdgcn_s_setprio(1);                                           \
    _Pragma("unroll") for (int mm = 0; mm < 4; mm++)                         \
      _Pragma("unroll") for (int nn = 0; nn < 2; nn++) {                     \
        acc[(qm) * 4 + mm][(qn) * 2 + nn] =                                  \
            __builtin_amdgcn_mfma_f32_16x16x32_bf16(                         \
                a_[mm][0], b_[nn][0], acc[(qm) * 4 + mm][(qn) * 2 + nn],     \
                0, 0, 0);                                                    \
        acc[(qm) * 4 + mm][(qn) * 2 + nn] =                                  \
            __builtin_amdgcn_mfma_f32_16x16x32_bf16(                         \
                a_[mm][1], b_[nn][1], acc[(qm) * 4 + mm][(qn) * 2 + nn],     \
                0, 0, 0);                                                    \
      }                                                                      \
    __builtin_amdgcn_s_setprio(0);                                           \
    __builtin_amdgcn_sched_barrier(0);                                       \
    __builtin_amdgcn_s_barrier();                                            \
  } while (0)

__global__ __launch_bounds__(512, 2) void gemm8p_s_k(
    const unsigned short* __restrict__ A,   // Q rows [i][1024]
    const unsigned short* __restrict__ B,   // K rows (A + 512)
    unsigned short* __restrict__ C,         // E bf16 [i][4096]
    float* __restrict__ lsum, float scale) {
  const int z = blockIdx.z;
  const long SLAB2 = (long)NPIX * 1024;
  const long SLABP = (long)NPIX * NPIX;
  A += z * SLAB2;
  B += z * SLAB2;
  const int m0 = blockIdx.y * 256, n0 = blockIdx.x * 256;
  const int t = threadIdx.x;
  const int lane = t & 63, w = t >> 6;
  const int wr = w >> 2, wc = w & 3;
  const int fr = lane & 15, fq = lane >> 4;
  const int chx = fr & 7;
  const int o0_ = (fq ^ chx) * 8, o1_ = ((fq + 4) ^ chx) * 8;

  __shared__ __align__(16) unsigned short LDSu[2 * 32768];  // 128 KB

  f32x4 acc[8][4] = {};

  const int srow = t >> 3;                        // 0..63
  const int scol = ((t & 7) ^ (srow & 7)) * 8;    // pre-swizzled source col
  const unsigned short* gA = A + (long)(m0 + srow) * 1024 + scol;
  const unsigned short* gB = B + (long)(n0 + srow) * 1024 + scol;

  // prologue: tile 0 -> slot0 (A-h0, B-h0, A-h1, B-h1 = 8 loads in flight)
  SH(0, 0, 0, 0); SH(0, 1, 0, 0); SH(0, 0, 1, 0); SH(0, 1, 1, 0);

  const int NIT = 4;  // K=512 -> 8 K-tiles, 2 per iter
  for (int i = 0; i < NIT - 1; i++) {
    // group A: consume slot0 (tile 2i), stage tile 2i+1 -> slot1
    PH(0, 0, 0, 4, SH(1, 0, 0, 2 * i + 1));
    PH(0, 0, 1, 2, SH(1, 1, 0, 2 * i + 1));
    PH(0, 1, 0, -1, SH(1, 0, 1, 2 * i + 1));
    PH(0, 1, 1, -1, SH(1, 1, 1, 2 * i + 1));
    // group B: consume slot1 (tile 2i+1), stage tile 2i+2 -> slot0
    PH(1, 0, 0, 4, SH(0, 0, 0, 2 * i + 2));
    PH(1, 0, 1, 2, SH(0, 1, 0, 2 * i + 2));
    PH(1, 1, 0, -1, SH(0, 0, 1, 2 * i + 2));
    PH(1, 1, 1, -1, SH(0, 1, 1, 2 * i + 2));
  }
  // last iter: group A stages tile 7; group B drains (no staging)
  PH(0, 0, 0, 4, SH(1, 0, 0, 7));
  PH(0, 0, 1, 2, SH(1, 1, 0, 7));
  PH(0, 1, 0, -1, SH(1, 0, 1, 7));
  PH(0, 1, 1, -1, SH(1, 1, 1, 7));
  PH(1, 0, 0, 4, (void)0);
  PH(1, 0, 1, 0, (void)0);
  PH(1, 1, 0, -1, (void)0);
  PH(1, 1, 1, -1, (void)0);

  // epilogue: EXPSUM (C/D layout col=lane&15, row=(lane>>4)*4+r, m89-verified)
  float rsum[8][4];
  for (int i = 0; i < 8; i++)
    for (int r = 0; r < 4; r++) rsum[i][r] = 0.f;
  for (int i = 0; i < 8; i++) {
    int mg = m0 + i * 32 + wr * 16 + fq * 4;
    for (int j = 0; j < 4; j++) {
      int ng = n0 + j * 64 + wc * 16 + fr;
      for (int r = 0; r < 4; r++) {
        float v = exp2f(acc[i][j][r] * scale);
        rsum[i][r] += v;
        C[z * SLABP + (long)(mg + r) * 4096 + ng] = f2bf(v);
      }
    }
  }
  for (int i = 0; i < 8; i++)
    for (int r = 0; r < 4; r++) {
      float s = rsum[i][r];
      s += __shfl_xor(s, 1);
      s += __shfl_xor(s, 2);
      s += __shfl_xor(s, 4);
      s += __shfl_xor(s, 8);
      if (fr == 0)
        atomicAdd(&lsum[z * NPIX + m0 + i * 32 + wr * 16 + fq * 4 + r], s);
    }
}
#undef SH
#undef PH

// ---------------- generic bf16 gemm_bt (r6 core + XCD swizzle, r10-proven) ----------------
template <int XCDX, int OUTF32, int BIASM, bool RESID, bool SCALE, bool EXPSUM, bool ROWSCALE>
__global__ __launch_bounds__(256) void gemm_bt_k(
    const unsigned short* __restrict__ A, const unsigned short* __restrict__ B,
    void* __restrict__ Cv, const float* __restrict__ bias,
    const float* __restrict__ resid, float* __restrict__ lsum,
    int K, int lda, int ldb, int ldc,
    long sA, long sB, long sC, float scale) {
  int z = blockIdx.z;
  A += z * sA;
  B += z * sB;

  int bx = blockIdx.x, by = blockIdx.y;
  if (XCDX > 0) {
    int s = blockIdx.x + gridDim.x * blockIdx.y;
    int xcd = s & 7, idx = s >> 3;
    int rw = gridDim.x / XCDX;
    int rh = (gridDim.y * XCDX) >> 3;
    int rx0 = (xcd % XCDX) * rw, ry0 = (xcd / XCDX) * rh;
    bx = rx0 + idx % rw;
    by = ry0 + idx / rw;
  }
  const int n0 = bx * 128, m0 = by * 128;

  const int t = threadIdx.x;
  const int lane = t & 63, w = t >> 6;
  const int wr = w >> 1, wc = w & 1;

  __shared__ __align__(16) unsigned short As[128 * 64];
  __shared__ __align__(16) unsigned short Bs[128 * 64];

  f32x4 acc[4][4] = {};

  const int srow = t >> 3;
  const int scol = (((t & 7) ^ (srow & 7)) * 8);
  const unsigned short* ga = A + (long)(m0 + srow) * lda + scol;
  const unsigned short* gb = B + (long)(n0 + srow) * ldb + scol;
  char* lA = (char*)As + t * 16;
  char* lB = (char*)Bs + t * 16;
  const long stpa = (long)32 * lda;
  const long stpb = (long)32 * ldb;

  const int fr = lane & 15, fq = lane >> 4;
  const int chx = fr & 7;
  const unsigned short* rA = As + (wr * 64 + fr) * 64;
  const unsigned short* rB = Bs + (wc * 64 + fr) * 64;

  const int nkt = K >> 6;
  for (int kt = 0; kt < nkt; kt++) {
    const unsigned short* gak = ga + (long)kt * 64;
    const unsigned short* gbk = gb + (long)kt * 64;
    GLD16(gak, lA);
    GLD16(gak + stpa, lA + 4096);
    GLD16(gak + 2 * stpa, lA + 8192);
    GLD16(gak + 3 * stpa, lA + 12288);
    GLD16(gbk, lB);
    GLD16(gbk + stpb, lB + 4096);
    GLD16(gbk + 2 * stpb, lB + 8192);
    GLD16(gbk + 3 * stpb, lB + 12288);
    __syncthreads();
    for (int kk = 0; kk < 2; kk++) {
      const int offA = ((fq + kk * 4) ^ chx) * 8;
      bf16x8 af[4], bfr[4];
      for (int i = 0; i < 4; i++) af[i] = *(const bf16x8*)(rA + i * 1024 + offA);
      for (int i = 0; i < 4; i++) bfr[i] = *(const bf16x8*)(rB + i * 1024 + offA);
      for (int i = 0; i < 4; i++)
        for (int j = 0; j < 4; j++)
          acc[i][j] = __builtin_amdgcn_mfma_f32_16x16x32_bf16(af[i], bfr[j], acc[i][j], 0, 0, 0);
    }
    __syncthreads();
  }

  if (OUTF32) {
    float* Cf = (float*)Cv;
    for (int i = 0; i < 4; i++) {
      int mg = m0 + wr * 64 + i * 16 + fq * 4;
      for (int j = 0; j < 4; j++) {
        int ng = n0 + wc * 64 + j * 16 + fr;
        for (int r = 0; r < 4; r++) {
          float v = acc[i][j][r];
          if (SCALE) v *= scale;
          int m = mg + r;
          if (BIASM == 1) v += bias[m];
          else if (BIASM == 2) v += bias[ng];
          long off = z * sC + (long)m * ldc + ng;
          if (RESID) v += resid[off];
          Cf[off] = v;
        }
      }
    }
  } else {
    float linv[4][4];
    if (ROWSCALE) {
      for (int i = 0; i < 4; i++)
        for (int r = 0; r < 4; r++)
          linv[i][r] = 1.f / lsum[z * NPIX + m0 + wr * 64 + i * 16 + fq * 4 + r];
    }
    float rsum[4][4];
    if (EXPSUM) {
      for (int i = 0; i < 4; i++)
        for (int r = 0; r < 4; r++) rsum[i][r] = 0.f;
    }
    unsigned short* Cb = (unsigned short*)Cv;
    for (int i = 0; i < 4; i++) {
      int mg = m0 + wr * 64 + i * 16 + fq * 4;
      for (int j = 0; j < 4; j++) {
        int ng = n0 + wc * 64 + j * 16 + fr;
        for (int r = 0; r < 4; r++) {
          float v = acc[i][j][r];
          if (SCALE) v *= scale;
          if (BIASM == 1) v += bias[mg + r];
          else if (BIASM == 2) v += bias[ng];
          if (EXPSUM) { v = exp2f(v); rsum[i][r] += v; }
          if (ROWSCALE) v *= linv[i][r];
          Cb[z * sC + (long)(mg + r) * ldc + ng] = f2bf(v);
        }
      }
    }
    if (EXPSUM) {
      for (int i = 0; i < 4; i++)
        for (int r = 0; r < 4; r++) {
          float s = rsum[i][r];
          s += __shfl_xor(s, 1);
          s += __shfl_xor(s, 2);
          s += __shfl_xor(s, 4);
          s += __shfl_xor(s, 8);
          if (fr == 0)
            atomicAdd(&lsum[z * NPIX + m0 + wr * 64 + i * 16 + fq * 4 + r], s);
        }
    }
  }
}

extern "C" void kernel_launch(void* const* d_in, const int* in_sizes, int n_in,
                              void* d_out, int out_size, void* d_ws, size_t ws_size,
                              hipStream_t stream) {
  const float* x  = (const float*)d_in[0];
  const float* wq = (const float*)d_in[1];
  const float* bq = (const float*)d_in[2];
  const float* wk = (const float*)d_in[3];
  const float* bk = (const float*)d_in[4];
  const float* wv = (const float*)d_in[5];
  const float* bv = (const float*)d_in[6];
  const float* wp = (const float*)d_in[7];
  const float* bp = (const float*)d_in[8];

  char* ws = (char*)d_ws;
  const long SLAB = (long)NPIX * CCH;
  const long SLAB2 = (long)NPIX * 1024;
  const long SLABP = (long)NPIX * NPIX;

  float* stats = (float*)ws;
  float* bqk = (float*)(ws + (32l << 10));
  float* lsum = (float*)(ws + (64l << 10));
  unsigned short* wbf = (unsigned short*)(ws + (192l << 10));
  unsigned short* hnT = (unsigned short*)(ws + (192l << 10) + (1l << 21));
  unsigned short* QKt = hnT + 4 * SLAB;
  unsigned short* V   = QKt + 4 * SLAB2;
  unsigned short* Ot  = V + 4 * SLAB;
  unsigned short* S4  = Ot + 4 * SLAB;

  unsigned short* wv_bf = wbf + 2 * 262144;
  unsigned short* wp_bf = wbf + 3 * 262144;

  cast_weights_k<<<dim3(1024, 4, 1), 256, 0, stream>>>(wq, wk, wv, wp, wbf);
  bias_concat_k<<<dim3(4, 1, 1), 256, 0, stream>>>(bq, bk, bqk);
  zero_l_k<<<dim3(16, 1, 1), 256, 0, stream>>>(lsum);
  stats_k<<<dim3(NB * CCH, 1, 1), 256, 0, stream>>>(x, stats);
  norm_t_k<<<dim3(128, 16, 4), 256, 0, stream>>>(x, stats, hnT);

  // QKt[b][i][n] = hnT[b] . [wq;wk]^T + bqk
  gemm_bt_k<1, 0, 2, false, false, false, false><<<dim3(8, 32, 4), 256, 0, stream>>>(
      hnT, wbf, QKt, bqk, nullptr, nullptr, 512, 512, 512, 1024, SLAB, 0, SLAB2, 1.f);
  // V[b][o][j] = Wv . hnT[b]^T + bv
  gemm_bt_k<2, 0, 1, false, false, false, false><<<dim3(32, 4, 4), 256, 0, stream>>>(
      wv_bf, hnT, V, bv, nullptr, nullptr, 512, 512, 512, 4096, 0, SLAB, SLAB, 1.f);

  // scale = (1/sqrt(512)) * log2(e)
  const float isc2 = 0.06375871387551278f;
  // E = exp(Q.K^T/sqrt(C)) via 8-phase 256^2 kernel
  gemm8p_s_k<<<dim3(16, 16, 4), 512, 0, stream>>>(QKt, QKt + 512, S4, lsum, isc2);
  // Ot[b][i][c] = (E[b] . V[b]^T) / lsum[b][i]
  gemm_bt_k<1, 0, 0, false, false, false, true><<<dim3(4, 32, 4), 256, 0, stream>>>(
      S4, V, Ot, nullptr, nullptr, lsum, 4096, 4096, 4096, 512, SLABP, SLAB, SLAB, 1.f);
  // out[b][o][i] = x + Wp . Ot[b]^T + bp
  gemm_bt_k<2, 1, 1, true, false, false, false><<<dim3(32, 4, 4), 256, 0, stream>>>(
      wp_bf, Ot, d_out, bp, x, nullptr, 512, 512, 512, 4096, 0, SLAB, SLAB, 1.f);
}

// Round 12
// 297.630 us; speedup vs baseline: 1.1430x; 1.0118x over previous
//
#include <hip/hip_runtime.h>
#include <hip/hip_bf16.h>

typedef short bf16x8 __attribute__((ext_vector_type(8)));
typedef float f32x4 __attribute__((ext_vector_type(4)));

#define CCH 512
#define NPIX 4096
#define NB 4

__device__ inline unsigned short f2bf(float f) {
  union { __hip_bfloat16 h; unsigned short u; } cv;
  cv.h = __float2bfloat16(f);
  return cv.u;
}

#define GLD16(gp, lp) __builtin_amdgcn_global_load_lds( \
    (const __attribute__((address_space(1))) unsigned int*)(gp), \
    (__attribute__((address_space(3))) unsigned int*)(lp), 16, 0, 0)

// ---------------- weight fp32 -> bf16 cast ----------------
__global__ __launch_bounds__(256) void cast_weights_k(
    const float* __restrict__ w0, const float* __restrict__ w1,
    const float* __restrict__ w2, const float* __restrict__ w3,
    unsigned short* __restrict__ out) {
  int z = blockIdx.y;
  const float* src = (z == 0) ? w0 : (z == 1) ? w1 : (z == 2) ? w2 : w3;
  long i = (long)blockIdx.x * 256 + threadIdx.x;
  out[(long)z * CCH * CCH + i] = f2bf(src[i]);
}

// ---------------- concat bq,bk -> bqk[1024] ----------------
__global__ __launch_bounds__(256) void bias_concat_k(
    const float* __restrict__ bq, const float* __restrict__ bk,
    float* __restrict__ bqk) {
  int i = blockIdx.x * 256 + threadIdx.x;
  bqk[i] = (i < CCH) ? bq[i] : bk[i - CCH];
}

// ---------------- zero the softmax row-sum accumulator ----------------
__global__ __launch_bounds__(256) void zero_l_k(float* __restrict__ lsum) {
  int i = (blockIdx.x * 256 + threadIdx.x) * 4;
  *(float4*)(lsum + i) = make_float4(0.f, 0.f, 0.f, 0.f);
}

// ---------------- instance-norm stats: one block per (b,c) plane ----------------
__global__ __launch_bounds__(256) void stats_k(const float* __restrict__ x,
                                               float* __restrict__ stats) {
  long plane = blockIdx.x;
  const float4* p = (const float4*)(x + plane * NPIX);
  int t = threadIdx.x;
  float s = 0.f, q = 0.f;
  for (int c = 0; c < 4; c++) {
    float4 v = p[c * 256 + t];
    s += v.x + v.y + v.z + v.w;
    q += v.x * v.x + v.y * v.y + v.z * v.z + v.w * v.w;
  }
  for (int off = 32; off; off >>= 1) { s += __shfl_xor(s, off); q += __shfl_xor(q, off); }
  __shared__ float rs[4], rq[4];
  int w = t >> 6;
  if ((t & 63) == 0) { rs[w] = s; rq[w] = q; }
  __syncthreads();
  if (t == 0) {
    s = rs[0] + rs[1] + rs[2] + rs[3];
    q = rq[0] + rq[1] + rq[2] + rq[3];
    float mu = s * (1.f / NPIX);
    float var = q * (1.f / NPIX) - mu * mu;
    stats[2 * plane] = mu;
    stats[2 * plane + 1] = rsqrtf(var + 1e-5f);
  }
}

// ---------------- normalize + transpose: x[b][c][i] -> hnT[b][i][c] bf16 ----------------
__global__ __launch_bounds__(256) void norm_t_k(const float* __restrict__ x,
                                                const float* __restrict__ stats,
                                                unsigned short* __restrict__ hnT) {
  int b = blockIdx.z;
  int c0 = blockIdx.y * 32, i0 = blockIdx.x * 32;
  __shared__ float tile[32][33];
  int t = threadIdx.x;
  int il = t & 31, cl = t >> 5;  // cl in 0..7
  for (int r = 0; r < 4; r++) {
    int c = c0 + cl + r * 8;
    long pl = (long)b * CCH + c;
    float mu = stats[2 * pl], rsg = stats[2 * pl + 1];
    tile[cl + r * 8][il] = (x[pl * NPIX + i0 + il] - mu) * rsg;
  }
  __syncthreads();
  for (int r = 0; r < 4; r++) {
    int i = i0 + cl + r * 8;
    hnT[((long)b * NPIX + i) * CCH + c0 + il] = f2bf(tile[il][cl + r * 8]);
  }
}

// ================= 8-phase 256x256 S-kernel (register-reuse phases) ==========
// E[b][i][j] = exp2(scale * Q.K^T), lsum[b][i] += row sums. K=512 fixed.
// 8 waves; STRIDED frags: m-frag j rows j*32+wr*16, n-frag j cols j*64+wc*16.
// Per K-tile group (4 phases), quadrant order (0,0)->(0,1)->(1,1)->(1,0) with
// operand regs held across phases: P0 reads A0+B0 (12), P1 reads B1 (4),
// P2 reads A1 (8), P3 reads NOTHING. 24 ds_read_b128/K-tile/wave (was 48) ->
// DS pipe ~750cy vs MFMA ~620cy per K-tile: balanced (was 2.4x DS-bound).
// vmcnt ledger (r11-proven): P0 waits vmcnt(4), P1 vmcnt(2); stage 1 half-tile
// per phase into the other slot; tail group drains with vmcnt(0) at P1.
#define SH(sl, ha, h, kt) do {                                               \
    const unsigned short* g_ = ((ha) ? gB : gA) + (long)(kt) * 64 +          \
                               (long)(2 * (h)) * 65536;                      \
    char* l_ = (char*)LDSu + (sl) * 65536 + (ha) * 32768 + (2 * (h)) * 8192  \
               + t * 16;                                                     \
    GLD16(g_, l_);                                                           \
    GLD16(g_ + 65536, l_ + 8192);                                            \
  } while (0)

#define READ_A(sl, half) do {                                                \
    const unsigned short* sa_ = LDSu + (sl) * 32768;                         \
    _Pragma("unroll") for (int mm = 0; mm < 4; mm++) {                       \
      int row = ((half) * 4 + mm) * 32 + wr * 16 + fr;                       \
      a_[mm][0] = *(const bf16x8*)(sa_ + row * 64 + o0_);                    \
      a_[mm][1] = *(const bf16x8*)(sa_ + row * 64 + o1_);                    \
    }                                                                        \
  } while (0)

#define READ_B(sl, half, dst) do {                                           \
    const unsigned short* sb_ = LDSu + (sl) * 32768 + 16384;                 \
    _Pragma("unroll") for (int nn = 0; nn < 2; nn++) {                       \
      int row = ((half) * 2 + nn) * 64 + wc * 16 + fr;                       \
      dst[nn][0] = *(const bf16x8*)(sb_ + row * 64 + o0_);                   \
      dst[nn][1] = *(const bf16x8*)(sb_ + row * 64 + o1_);                   \
    }                                                                        \
  } while (0)

#define MF(qm, qn, bb)                                                       \
    _Pragma("unroll") for (int mm = 0; mm < 4; mm++)                         \
      _Pragma("unroll") for (int nn = 0; nn < 2; nn++) {                     \
        acc[(qm) * 4 + mm][(qn) * 2 + nn] =                                  \
            __builtin_amdgcn_mfma_f32_16x16x32_bf16(                         \
                a_[mm][0], bb[nn][0], acc[(qm) * 4 + mm][(qn) * 2 + nn],     \
                0, 0, 0);                                                    \
        acc[(qm) * 4 + mm][(qn) * 2 + nn] =                                  \
            __builtin_amdgcn_mfma_f32_16x16x32_bf16(                         \
                a_[mm][1], bb[nn][1], acc[(qm) * 4 + mm][(qn) * 2 + nn],     \
                0, 0, 0);                                                    \
      }

#define PHASE(WN, SSTMT, RSTMT, MSTMT) do {                                  \
    if ((WN) == 4) asm volatile("s_waitcnt vmcnt(4)" ::: "memory");          \
    else if ((WN) == 2) asm volatile("s_waitcnt vmcnt(2)" ::: "memory");     \
    else if ((WN) == 0) asm volatile("s_waitcnt vmcnt(0)" ::: "memory");     \
    __builtin_amdgcn_s_barrier();                                            \
    __builtin_amdgcn_sched_barrier(0);                                       \
    SSTMT;                                                                   \
    RSTMT;                                                                   \
    asm volatile("s_waitcnt lgkmcnt(0)" ::: "memory");                       \
    __builtin_amdgcn_sched_barrier(0);                                       \
    __builtin_amdgcn_s_setprio(1);                                           \
    MSTMT;                                                                   \
    __builtin_amdgcn_s_setprio(0);                                           \
    __builtin_amdgcn_sched_barrier(0);                                       \
    __builtin_amdgcn_s_barrier();                                            \
  } while (0)

// one K-tile group: consume slot sl, stage tile ktn's 4 half-tiles into sl^1
#define GROUP(sl, ktn)                                                       \
    PHASE(4, SH(sl ^ 1, 0, 0, ktn),                                         \
          { READ_A(sl, 0); READ_B(sl, 0, b0_); }, MF(0, 0, b0_));            \
    PHASE(2, SH(sl ^ 1, 1, 0, ktn), READ_B(sl, 1, b1_), MF(0, 1, b1_));      \
    PHASE(-1, SH(sl ^ 1, 0, 1, ktn), READ_A(sl, 1), MF(1, 1, b1_));          \
    PHASE(-1, SH(sl ^ 1, 1, 1, ktn), (void)0, MF(1, 0, b0_))

#define GROUP_TAIL(sl)                                                       \
    PHASE(4, (void)0, { READ_A(sl, 0); READ_B(sl, 0, b0_); }, MF(0, 0, b0_));\
    PHASE(0, (void)0, READ_B(sl, 1, b1_), MF(0, 1, b1_));                    \
    PHASE(-1, (void)0, READ_A(sl, 1), MF(1, 1, b1_));                        \
    PHASE(-1, (void)0, (void)0, MF(1, 0, b0_))

__global__ __launch_bounds__(512, 2) void gemm8p_s_k(
    const unsigned short* __restrict__ A,   // Q rows [i][1024]
    const unsigned short* __restrict__ B,   // K rows (A + 512)
    unsigned short* __restrict__ C,         // E bf16 [i][4096]
    float* __restrict__ lsum, float scale) {
  const int z = blockIdx.z;
  const long SLAB2 = (long)NPIX * 1024;
  const long SLABP = (long)NPIX * NPIX;
  A += z * SLAB2;
  B += z * SLAB2;
  const int m0 = blockIdx.y * 256, n0 = blockIdx.x * 256;
  const int t = threadIdx.x;
  const int lane = t & 63, w = t >> 6;
  const int wr = w >> 2, wc = w & 3;
  const int fr = lane & 15, fq = lane >> 4;
  const int chx = fr & 7;
  const int o0_ = (fq ^ chx) * 8, o1_ = ((fq + 4) ^ chx) * 8;

  __shared__ __align__(16) unsigned short LDSu[2 * 32768];  // 128 KB

  f32x4 acc[8][4] = {};
  bf16x8 a_[4][2], b0_[2][2], b1_[2][2];

  const int srow = t >> 3;                        // 0..63
  const int scol = ((t & 7) ^ (srow & 7)) * 8;    // pre-swizzled source col
  const unsigned short* gA = A + (long)(m0 + srow) * 1024 + scol;
  const unsigned short* gB = B + (long)(n0 + srow) * 1024 + scol;

  // prologue: tile 0 -> slot0 (A-h0, B-h0, A-h1, B-h1 = 8 loads in flight)
  SH(0, 0, 0, 0); SH(0, 1, 0, 0); SH(0, 0, 1, 0); SH(0, 1, 1, 0);

  // K=512 -> 8 K-tiles: 7 staged groups + tail
  GROUP(0, 1); GROUP(1, 2);
  GROUP(0, 3); GROUP(1, 4);
  GROUP(0, 5); GROUP(1, 6);
  GROUP(0, 7);
  GROUP_TAIL(1);

  // epilogue: EXPSUM (C/D layout col=lane&15, row=(lane>>4)*4+r, m89-verified)
  float rsum[8][4];
  for (int i = 0; i < 8; i++)
    for (int r = 0; r < 4; r++) rsum[i][r] = 0.f;
  for (int i = 0; i < 8; i++) {
    int mg = m0 + i * 32 + wr * 16 + fq * 4;
    for (int j = 0; j < 4; j++) {
      int ng = n0 + j * 64 + wc * 16 + fr;
      for (int r = 0; r < 4; r++) {
        float v = exp2f(acc[i][j][r] * scale);
        rsum[i][r] += v;
        C[z * SLABP + (long)(mg + r) * 4096 + ng] = f2bf(v);
      }
    }
  }
  for (int i = 0; i < 8; i++)
    for (int r = 0; r < 4; r++) {
      float s = rsum[i][r];
      s += __shfl_xor(s, 1);
      s += __shfl_xor(s, 2);
      s += __shfl_xor(s, 4);
      s += __shfl_xor(s, 8);
      if (fr == 0)
        atomicAdd(&lsum[z * NPIX + m0 + i * 32 + wr * 16 + fq * 4 + r], s);
    }
}
#undef SH
#undef READ_A
#undef READ_B
#undef MF
#undef PHASE
#undef GROUP
#undef GROUP_TAIL

// ---------------- generic bf16 gemm_bt (r6 core + XCD swizzle, r10-proven) ----------------
template <int XCDX, int OUTF32, int BIASM, bool RESID, bool SCALE, bool EXPSUM, bool ROWSCALE>
__global__ __launch_bounds__(256) void gemm_bt_k(
    const unsigned short* __restrict__ A, const unsigned short* __restrict__ B,
    void* __restrict__ Cv, const float* __restrict__ bias,
    const float* __restrict__ resid, float* __restrict__ lsum,
    int K, int lda, int ldb, int ldc,
    long sA, long sB, long sC, float scale) {
  int z = blockIdx.z;
  A += z * sA;
  B += z * sB;

  int bx = blockIdx.x, by = blockIdx.y;
  if (XCDX > 0) {
    int s = blockIdx.x + gridDim.x * blockIdx.y;
    int xcd = s & 7, idx = s >> 3;
    int rw = gridDim.x / XCDX;
    int rh = (gridDim.y * XCDX) >> 3;
    int rx0 = (xcd % XCDX) * rw, ry0 = (xcd / XCDX) * rh;
    bx = rx0 + idx % rw;
    by = ry0 + idx / rw;
  }
  const int n0 = bx * 128, m0 = by * 128;

  const int t = threadIdx.x;
  const int lane = t & 63, w = t >> 6;
  const int wr = w >> 1, wc = w & 1;

  __shared__ __align__(16) unsigned short As[128 * 64];
  __shared__ __align__(16) unsigned short Bs[128 * 64];

  f32x4 acc[4][4] = {};

  const int srow = t >> 3;
  const int scol = (((t & 7) ^ (srow & 7)) * 8);
  const unsigned short* ga = A + (long)(m0 + srow) * lda + scol;
  const unsigned short* gb = B + (long)(n0 + srow) * ldb + scol;
  char* lA = (char*)As + t * 16;
  char* lB = (char*)Bs + t * 16;
  const long stpa = (long)32 * lda;
  const long stpb = (long)32 * ldb;

  const int fr = lane & 15, fq = lane >> 4;
  const int chx = fr & 7;
  const unsigned short* rA = As + (wr * 64 + fr) * 64;
  const unsigned short* rB = Bs + (wc * 64 + fr) * 64;

  const int nkt = K >> 6;
  for (int kt = 0; kt < nkt; kt++) {
    const unsigned short* gak = ga + (long)kt * 64;
    const unsigned short* gbk = gb + (long)kt * 64;
    GLD16(gak, lA);
    GLD16(gak + stpa, lA + 4096);
    GLD16(gak + 2 * stpa, lA + 8192);
    GLD16(gak + 3 * stpa, lA + 12288);
    GLD16(gbk, lB);
    GLD16(gbk + stpb, lB + 4096);
    GLD16(gbk + 2 * stpb, lB + 8192);
    GLD16(gbk + 3 * stpb, lB + 12288);
    __syncthreads();
    for (int kk = 0; kk < 2; kk++) {
      const int offA = ((fq + kk * 4) ^ chx) * 8;
      bf16x8 af[4], bfr[4];
      for (int i = 0; i < 4; i++) af[i] = *(const bf16x8*)(rA + i * 1024 + offA);
      for (int i = 0; i < 4; i++) bfr[i] = *(const bf16x8*)(rB + i * 1024 + offA);
      for (int i = 0; i < 4; i++)
        for (int j = 0; j < 4; j++)
          acc[i][j] = __builtin_amdgcn_mfma_f32_16x16x32_bf16(af[i], bfr[j], acc[i][j], 0, 0, 0);
    }
    __syncthreads();
  }

  if (OUTF32) {
    float* Cf = (float*)Cv;
    for (int i = 0; i < 4; i++) {
      int mg = m0 + wr * 64 + i * 16 + fq * 4;
      for (int j = 0; j < 4; j++) {
        int ng = n0 + wc * 64 + j * 16 + fr;
        for (int r = 0; r < 4; r++) {
          float v = acc[i][j][r];
          if (SCALE) v *= scale;
          int m = mg + r;
          if (BIASM == 1) v += bias[m];
          else if (BIASM == 2) v += bias[ng];
          long off = z * sC + (long)m * ldc + ng;
          if (RESID) v += resid[off];
          Cf[off] = v;
        }
      }
    }
  } else {
    float linv[4][4];
    if (ROWSCALE) {
      for (int i = 0; i < 4; i++)
        for (int r = 0; r < 4; r++)
          linv[i][r] = 1.f / lsum[z * NPIX + m0 + wr * 64 + i * 16 + fq * 4 + r];
    }
    float rsum[4][4];
    if (EXPSUM) {
      for (int i = 0; i < 4; i++)
        for (int r = 0; r < 4; r++) rsum[i][r] = 0.f;
    }
    unsigned short* Cb = (unsigned short*)Cv;
    for (int i = 0; i < 4; i++) {
      int mg = m0 + wr * 64 + i * 16 + fq * 4;
      for (int j = 0; j < 4; j++) {
        int ng = n0 + wc * 64 + j * 16 + fr;
        for (int r = 0; r < 4; r++) {
          float v = acc[i][j][r];
          if (SCALE) v *= scale;
          if (BIASM == 1) v += bias[mg + r];
          else if (BIASM == 2) v += bias[ng];
          if (EXPSUM) { v = exp2f(v); rsum[i][r] += v; }
          if (ROWSCALE) v *= linv[i][r];
          Cb[z * sC + (long)(mg + r) * ldc + ng] = f2bf(v);
        }
      }
    }
    if (EXPSUM) {
      for (int i = 0; i < 4; i++)
        for (int r = 0; r < 4; r++) {
          float s = rsum[i][r];
          s += __shfl_xor(s, 1);
          s += __shfl_xor(s, 2);
          s += __shfl_xor(s, 4);
          s += __shfl_xor(s, 8);
          if (fr == 0)
            atomicAdd(&lsum[z * NPIX + m0 + wr * 64 + i * 16 + fq * 4 + r], s);
        }
    }
  }
}

extern "C" void kernel_launch(void* const* d_in, const int* in_sizes, int n_in,
                              void* d_out, int out_size, void* d_ws, size_t ws_size,
                              hipStream_t stream) {
  const float* x  = (const float*)d_in[0];
  const float* wq = (const float*)d_in[1];
  const float* bq = (const float*)d_in[2];
  const float* wk = (const float*)d_in[3];
  const float* bk = (const float*)d_in[4];
  const float* wv = (const float*)d_in[5];
  const float* bv = (const float*)d_in[6];
  const float* wp = (const float*)d_in[7];
  const float* bp = (const float*)d_in[8];

  char* ws = (char*)d_ws;
  const long SLAB = (long)NPIX * CCH;
  const long SLAB2 = (long)NPIX * 1024;
  const long SLABP = (long)NPIX * NPIX;

  float* stats = (float*)ws;
  float* bqk = (float*)(ws + (32l << 10));
  float* lsum = (float*)(ws + (64l << 10));
  unsigned short* wbf = (unsigned short*)(ws + (192l << 10));
  unsigned short* hnT = (unsigned short*)(ws + (192l << 10) + (1l << 21));
  unsigned short* QKt = hnT + 4 * SLAB;
  unsigned short* V   = QKt + 4 * SLAB2;
  unsigned short* Ot  = V + 4 * SLAB;
  unsigned short* S4  = Ot + 4 * SLAB;

  unsigned short* wv_bf = wbf + 2 * 262144;
  unsigned short* wp_bf = wbf + 3 * 262144;

  cast_weights_k<<<dim3(1024, 4, 1), 256, 0, stream>>>(wq, wk, wv, wp, wbf);
  bias_concat_k<<<dim3(4, 1, 1), 256, 0, stream>>>(bq, bk, bqk);
  zero_l_k<<<dim3(16, 1, 1), 256, 0, stream>>>(lsum);
  stats_k<<<dim3(NB * CCH, 1, 1), 256, 0, stream>>>(x, stats);
  norm_t_k<<<dim3(128, 16, 4), 256, 0, stream>>>(x, stats, hnT);

  // QKt[b][i][n] = hnT[b] . [wq;wk]^T + bqk
  gemm_bt_k<1, 0, 2, false, false, false, false><<<dim3(8, 32, 4), 256, 0, stream>>>(
      hnT, wbf, QKt, bqk, nullptr, nullptr, 512, 512, 512, 1024, SLAB, 0, SLAB2, 1.f);
  // V[b][o][j] = Wv . hnT[b]^T + bv
  gemm_bt_k<2, 0, 1, false, false, false, false><<<dim3(32, 4, 4), 256, 0, stream>>>(
      wv_bf, hnT, V, bv, nullptr, nullptr, 512, 512, 512, 4096, 0, SLAB, SLAB, 1.f);

  // scale = (1/sqrt(512)) * log2(e)
  const float isc2 = 0.06375871387551278f;
  // E = exp(Q.K^T/sqrt(C)) via 8-phase 256^2 kernel
  gemm8p_s_k<<<dim3(16, 16, 4), 512, 0, stream>>>(QKt, QKt + 512, S4, lsum, isc2);
  // Ot[b][i][c] = (E[b] . V[b]^T) / lsum[b][i]
  gemm_bt_k<1, 0, 0, false, false, false, true><<<dim3(4, 32, 4), 256, 0, stream>>>(
      S4, V, Ot, nullptr, nullptr, lsum, 4096, 4096, 4096, 512, SLABP, SLAB, SLAB, 1.f);
  // out[b][o][i] = x + Wp . Ot[b]^T + bp
  gemm_bt_k<2, 1, 1, true, false, false, false><<<dim3(32, 4, 4), 256, 0, stream>>>(
      wp_bf, Ot, d_out, bp, x, nullptr, 512, 512, 512, 4096, 0, SLAB, SLAB, 1.f);
}

// Round 13
// 294.031 us; speedup vs baseline: 1.1570x; 1.0122x over previous
//
#include <hip/hip_runtime.h>
#include <hip/hip_bf16.h>

typedef short bf16x8 __attribute__((ext_vector_type(8)));
typedef float f32x4 __attribute__((ext_vector_type(4)));

#define CCH 512
#define NPIX 4096
#define NB 4

__device__ inline unsigned short f2bf(float f) {
  union { __hip_bfloat16 h; unsigned short u; } cv;
  cv.h = __float2bfloat16(f);
  return cv.u;
}

#define GLD16(gp, lp) __builtin_amdgcn_global_load_lds( \
    (const __attribute__((address_space(1))) unsigned int*)(gp), \
    (__attribute__((address_space(3))) unsigned int*)(lp), 16, 0, 0)

// ---------------- weight fp32 -> bf16 cast ----------------
__global__ __launch_bounds__(256) void cast_weights_k(
    const float* __restrict__ w0, const float* __restrict__ w1,
    const float* __restrict__ w2, const float* __restrict__ w3,
    unsigned short* __restrict__ out) {
  int z = blockIdx.y;
  const float* src = (z == 0) ? w0 : (z == 1) ? w1 : (z == 2) ? w2 : w3;
  long i = (long)blockIdx.x * 256 + threadIdx.x;
  out[(long)z * CCH * CCH + i] = f2bf(src[i]);
}

// ---------------- concat bq,bk -> bqk[1024] ----------------
__global__ __launch_bounds__(256) void bias_concat_k(
    const float* __restrict__ bq, const float* __restrict__ bk,
    float* __restrict__ bqk) {
  int i = blockIdx.x * 256 + threadIdx.x;
  bqk[i] = (i < CCH) ? bq[i] : bk[i - CCH];
}

// ---------------- zero the softmax row-sum accumulator ----------------
__global__ __launch_bounds__(256) void zero_l_k(float* __restrict__ lsum) {
  int i = (blockIdx.x * 256 + threadIdx.x) * 4;
  *(float4*)(lsum + i) = make_float4(0.f, 0.f, 0.f, 0.f);
}

// ---------------- instance-norm stats: one block per (b,c) plane ----------------
__global__ __launch_bounds__(256) void stats_k(const float* __restrict__ x,
                                               float* __restrict__ stats) {
  long plane = blockIdx.x;
  const float4* p = (const float4*)(x + plane * NPIX);
  int t = threadIdx.x;
  float s = 0.f, q = 0.f;
  for (int c = 0; c < 4; c++) {
    float4 v = p[c * 256 + t];
    s += v.x + v.y + v.z + v.w;
    q += v.x * v.x + v.y * v.y + v.z * v.z + v.w * v.w;
  }
  for (int off = 32; off; off >>= 1) { s += __shfl_xor(s, off); q += __shfl_xor(q, off); }
  __shared__ float rs[4], rq[4];
  int w = t >> 6;
  if ((t & 63) == 0) { rs[w] = s; rq[w] = q; }
  __syncthreads();
  if (t == 0) {
    s = rs[0] + rs[1] + rs[2] + rs[3];
    q = rq[0] + rq[1] + rq[2] + rq[3];
    float mu = s * (1.f / NPIX);
    float var = q * (1.f / NPIX) - mu * mu;
    stats[2 * plane] = mu;
    stats[2 * plane + 1] = rsqrtf(var + 1e-5f);
  }
}

// ---------------- normalize + transpose: x[b][c][i] -> hnT[b][i][c] bf16 ----------------
__global__ __launch_bounds__(256) void norm_t_k(const float* __restrict__ x,
                                                const float* __restrict__ stats,
                                                unsigned short* __restrict__ hnT) {
  int b = blockIdx.z;
  int c0 = blockIdx.y * 32, i0 = blockIdx.x * 32;
  __shared__ float tile[32][33];
  int t = threadIdx.x;
  int il = t & 31, cl = t >> 5;  // cl in 0..7
  for (int r = 0; r < 4; r++) {
    int c = c0 + cl + r * 8;
    long pl = (long)b * CCH + c;
    float mu = stats[2 * pl], rsg = stats[2 * pl + 1];
    tile[cl + r * 8][il] = (x[pl * NPIX + i0 + il] - mu) * rsg;
  }
  __syncthreads();
  for (int r = 0; r < 4; r++) {
    int i = i0 + cl + r * 8;
    hnT[((long)b * NPIX + i) * CCH + c0 + il] = f2bf(tile[il][cl + r * 8]);
  }
}

// ================= 8-phase 256x256 S-kernel (pre-barrier reads) =============
// E[b][i][j] = exp2(scale * Q.K^T), lsum[b][i] += row sums. K=512 fixed.
// Key fix vs r12: ds_reads and staging are issued BEFORE the phase's barrier;
// between the barrier pair there is ONLY {lgkmcnt(0); MFMA} — s_barrier does
// not drain the MFMA pipe, so phase p-1's MFMAs execute concurrently with
// phase p's DS processing (m201 mechanism). Legality: reads of slot sl (tile g)
// are validated at group g-1's P3 {vmcnt(8); barrier} — 2-tile-deep staging
// (prologue stages tiles 0,1; group g stages tile g+2 into sub-slots freed
// phase-by-phase: P1 stages A0+B0 (freed P0), P2 stages B1 (freed P1),
// P3 stages A1 (freed P2); each write separated from its last reader by a
// full barrier pair). vmcnt(8) at P3 = exactly tile g+2's in-flight loads.
#define SH(sl, ha, h, kt) do {                                               \
    const unsigned short* g_ = ((ha) ? gB : gA) + (long)(kt) * 64 +          \
                               (long)(2 * (h)) * 65536;                      \
    char* l_ = (char*)LDSu + (sl) * 65536 + (ha) * 32768 + (2 * (h)) * 8192  \
               + t * 16;                                                     \
    GLD16(g_, l_);                                                           \
    GLD16(g_ + 65536, l_ + 8192);                                            \
  } while (0)

#define READ_A(sl, half) do {                                                \
    const unsigned short* sa_ = LDSu + (sl) * 32768;                         \
    _Pragma("unroll") for (int mm = 0; mm < 4; mm++) {                       \
      int row = ((half) * 4 + mm) * 32 + wr * 16 + fr;                       \
      a_[mm][0] = *(const bf16x8*)(sa_ + row * 64 + o0_);                    \
      a_[mm][1] = *(const bf16x8*)(sa_ + row * 64 + o1_);                    \
    }                                                                        \
  } while (0)

#define READ_B(sl, half, dst) do {                                           \
    const unsigned short* sb_ = LDSu + (sl) * 32768 + 16384;                 \
    _Pragma("unroll") for (int nn = 0; nn < 2; nn++) {                       \
      int row = ((half) * 2 + nn) * 64 + wc * 16 + fr;                       \
      dst[nn][0] = *(const bf16x8*)(sb_ + row * 64 + o0_);                   \
      dst[nn][1] = *(const bf16x8*)(sb_ + row * 64 + o1_);                   \
    }                                                                        \
  } while (0)

#define MF(qm, qn, bb)                                                       \
    _Pragma("unroll") for (int mm = 0; mm < 4; mm++)                         \
      _Pragma("unroll") for (int nn = 0; nn < 2; nn++) {                     \
        acc[(qm) * 4 + mm][(qn) * 2 + nn] =                                  \
            __builtin_amdgcn_mfma_f32_16x16x32_bf16(                         \
                a_[mm][0], bb[nn][0], acc[(qm) * 4 + mm][(qn) * 2 + nn],     \
                0, 0, 0);                                                    \
        acc[(qm) * 4 + mm][(qn) * 2 + nn] =                                  \
            __builtin_amdgcn_mfma_f32_16x16x32_bf16(                         \
                a_[mm][1], bb[nn][1], acc[(qm) * 4 + mm][(qn) * 2 + nn],     \
                0, 0, 0);                                                    \
      }

// stage + reads issued PRE-barrier; only lgkm-wait + MFMA between barriers.
#define PHASE(VN, SSTMT, RSTMT, MSTMT) do {                                  \
    SSTMT;                                                                   \
    RSTMT;                                                                   \
    if ((VN) == 8) asm volatile("s_waitcnt vmcnt(8)" ::: "memory");          \
    else if ((VN) == 0) asm volatile("s_waitcnt vmcnt(0)" ::: "memory");     \
    __builtin_amdgcn_s_barrier();                                            \
    asm volatile("s_waitcnt lgkmcnt(0)" ::: "memory");                       \
    __builtin_amdgcn_sched_barrier(0);                                       \
    __builtin_amdgcn_s_setprio(1);                                           \
    MSTMT;                                                                   \
    __builtin_amdgcn_s_setprio(0);                                           \
    __builtin_amdgcn_sched_barrier(0);                                       \
    __builtin_amdgcn_s_barrier();                                            \
  } while (0)

// staged group: consume slot sl (tile g), stage tile tn=g+2 into freed sub-slots
#define GROUP_S(sl, tn)                                                      \
    PHASE(-1, (void)0, { READ_A(sl, 0); READ_B(sl, 0, b0_); }, MF(0, 0, b0_)); \
    PHASE(-1, { SH(sl, 0, 0, tn); SH(sl, 1, 0, tn); },                       \
          READ_B(sl, 1, b1_), MF(0, 1, b1_));                                \
    PHASE(-1, SH(sl, 1, 1, tn), READ_A(sl, 1), MF(1, 1, b1_));               \
    PHASE(8, SH(sl, 0, 1, tn), (void)0, MF(1, 0, b0_))

// unstaged group: VN3 = vmcnt at P3 (0 to validate the final tile, -1 none)
#define GROUP_N(sl, VN3)                                                     \
    PHASE(-1, (void)0, { READ_A(sl, 0); READ_B(sl, 0, b0_); }, MF(0, 0, b0_)); \
    PHASE(-1, (void)0, READ_B(sl, 1, b1_), MF(0, 1, b1_));                   \
    PHASE(-1, (void)0, READ_A(sl, 1), MF(1, 1, b1_));                        \
    PHASE(VN3, (void)0, (void)0, MF(1, 0, b0_))

__global__ __launch_bounds__(512, 2) void gemm8p_s_k(
    const unsigned short* __restrict__ A,   // Q rows [i][1024]
    const unsigned short* __restrict__ B,   // K rows (A + 512)
    unsigned short* __restrict__ C,         // E bf16 [i][4096]
    float* __restrict__ lsum, float scale) {
  const int z = blockIdx.z;
  const long SLAB2 = (long)NPIX * 1024;
  const long SLABP = (long)NPIX * NPIX;
  A += z * SLAB2;
  B += z * SLAB2;
  const int m0 = blockIdx.y * 256, n0 = blockIdx.x * 256;
  const int t = threadIdx.x;
  const int lane = t & 63, w = t >> 6;
  const int wr = w >> 2, wc = w & 3;
  const int fr = lane & 15, fq = lane >> 4;
  const int chx = fr & 7;
  const int o0_ = (fq ^ chx) * 8, o1_ = ((fq + 4) ^ chx) * 8;

  __shared__ __align__(16) unsigned short LDSu[2 * 32768];  // 128 KB

  f32x4 acc[8][4] = {};
  bf16x8 a_[4][2], b0_[2][2], b1_[2][2];

  const int srow = t >> 3;                        // 0..63
  const int scol = ((t & 7) ^ (srow & 7)) * 8;    // pre-swizzled source col
  const unsigned short* gA = A + (long)(m0 + srow) * 1024 + scol;
  const unsigned short* gB = B + (long)(n0 + srow) * 1024 + scol;

  // prologue: tiles 0,1 -> slots 0,1 (16 loads); vmcnt(8) validates tile 0
  SH(0, 0, 0, 0); SH(0, 1, 0, 0); SH(0, 0, 1, 0); SH(0, 1, 1, 0);
  SH(1, 0, 0, 1); SH(1, 1, 0, 1); SH(1, 0, 1, 1); SH(1, 1, 1, 1);
  asm volatile("s_waitcnt vmcnt(8)" ::: "memory");
  __builtin_amdgcn_s_barrier();

  // K=512 -> 8 K-tiles; groups 0..5 stage tiles 2..7; groups 6,7 drain
  GROUP_S(0, 2); GROUP_S(1, 3);
  GROUP_S(0, 4); GROUP_S(1, 5);
  GROUP_S(0, 6); GROUP_S(1, 7);
  GROUP_N(0, 0);
  GROUP_N(1, -1);

  // epilogue: EXPSUM (C/D layout col=lane&15, row=(lane>>4)*4+r, m89-verified)
  float rsum[8][4];
  for (int i = 0; i < 8; i++)
    for (int r = 0; r < 4; r++) rsum[i][r] = 0.f;
  for (int i = 0; i < 8; i++) {
    int mg = m0 + i * 32 + wr * 16 + fq * 4;
    for (int j = 0; j < 4; j++) {
      int ng = n0 + j * 64 + wc * 16 + fr;
      for (int r = 0; r < 4; r++) {
        float v = exp2f(acc[i][j][r] * scale);
        rsum[i][r] += v;
        C[z * SLABP + (long)(mg + r) * 4096 + ng] = f2bf(v);
      }
    }
  }
  for (int i = 0; i < 8; i++)
    for (int r = 0; r < 4; r++) {
      float s = rsum[i][r];
      s += __shfl_xor(s, 1);
      s += __shfl_xor(s, 2);
      s += __shfl_xor(s, 4);
      s += __shfl_xor(s, 8);
      if (fr == 0)
        atomicAdd(&lsum[z * NPIX + m0 + i * 32 + wr * 16 + fq * 4 + r], s);
    }
}
#undef SH
#undef READ_A
#undef READ_B
#undef MF
#undef PHASE
#undef GROUP_S
#undef GROUP_N

// ---------------- generic bf16 gemm_bt (r6 core + XCD swizzle, r10-proven) ----------------
template <int XCDX, int OUTF32, int BIASM, bool RESID, bool SCALE, bool EXPSUM, bool ROWSCALE>
__global__ __launch_bounds__(256) void gemm_bt_k(
    const unsigned short* __restrict__ A, const unsigned short* __restrict__ B,
    void* __restrict__ Cv, const float* __restrict__ bias,
    const float* __restrict__ resid, float* __restrict__ lsum,
    int K, int lda, int ldb, int ldc,
    long sA, long sB, long sC, float scale) {
  int z = blockIdx.z;
  A += z * sA;
  B += z * sB;

  int bx = blockIdx.x, by = blockIdx.y;
  if (XCDX > 0) {
    int s = blockIdx.x + gridDim.x * blockIdx.y;
    int xcd = s & 7, idx = s >> 3;
    int rw = gridDim.x / XCDX;
    int rh = (gridDim.y * XCDX) >> 3;
    int rx0 = (xcd % XCDX) * rw, ry0 = (xcd / XCDX) * rh;
    bx = rx0 + idx % rw;
    by = ry0 + idx / rw;
  }
  const int n0 = bx * 128, m0 = by * 128;

  const int t = threadIdx.x;
  const int lane = t & 63, w = t >> 6;
  const int wr = w >> 1, wc = w & 1;

  __shared__ __align__(16) unsigned short As[128 * 64];
  __shared__ __align__(16) unsigned short Bs[128 * 64];

  f32x4 acc[4][4] = {};

  const int srow = t >> 3;
  const int scol = (((t & 7) ^ (srow & 7)) * 8);
  const unsigned short* ga = A + (long)(m0 + srow) * lda + scol;
  const unsigned short* gb = B + (long)(n0 + srow) * ldb + scol;
  char* lA = (char*)As + t * 16;
  char* lB = (char*)Bs + t * 16;
  const long stpa = (long)32 * lda;
  const long stpb = (long)32 * ldb;

  const int fr = lane & 15, fq = lane >> 4;
  const int chx = fr & 7;
  const unsigned short* rA = As + (wr * 64 + fr) * 64;
  const unsigned short* rB = Bs + (wc * 64 + fr) * 64;

  const int nkt = K >> 6;
  for (int kt = 0; kt < nkt; kt++) {
    const unsigned short* gak = ga + (long)kt * 64;
    const unsigned short* gbk = gb + (long)kt * 64;
    GLD16(gak, lA);
    GLD16(gak + stpa, lA + 4096);
    GLD16(gak + 2 * stpa, lA + 8192);
    GLD16(gak + 3 * stpa, lA + 12288);
    GLD16(gbk, lB);
    GLD16(gbk + stpb, lB + 4096);
    GLD16(gbk + 2 * stpb, lB + 8192);
    GLD16(gbk + 3 * stpb, lB + 12288);
    __syncthreads();
    for (int kk = 0; kk < 2; kk++) {
      const int offA = ((fq + kk * 4) ^ chx) * 8;
      bf16x8 af[4], bfr[4];
      for (int i = 0; i < 4; i++) af[i] = *(const bf16x8*)(rA + i * 1024 + offA);
      for (int i = 0; i < 4; i++) bfr[i] = *(const bf16x8*)(rB + i * 1024 + offA);
      for (int i = 0; i < 4; i++)
        for (int j = 0; j < 4; j++)
          acc[i][j] = __builtin_amdgcn_mfma_f32_16x16x32_bf16(af[i], bfr[j], acc[i][j], 0, 0, 0);
    }
    __syncthreads();
  }

  if (OUTF32) {
    float* Cf = (float*)Cv;
    for (int i = 0; i < 4; i++) {
      int mg = m0 + wr * 64 + i * 16 + fq * 4;
      for (int j = 0; j < 4; j++) {
        int ng = n0 + wc * 64 + j * 16 + fr;
        for (int r = 0; r < 4; r++) {
          float v = acc[i][j][r];
          if (SCALE) v *= scale;
          int m = mg + r;
          if (BIASM == 1) v += bias[m];
          else if (BIASM == 2) v += bias[ng];
          long off = z * sC + (long)m * ldc + ng;
          if (RESID) v += resid[off];
          Cf[off] = v;
        }
      }
    }
  } else {
    float linv[4][4];
    if (ROWSCALE) {
      for (int i = 0; i < 4; i++)
        for (int r = 0; r < 4; r++)
          linv[i][r] = 1.f / lsum[z * NPIX + m0 + wr * 64 + i * 16 + fq * 4 + r];
    }
    float rsum[4][4];
    if (EXPSUM) {
      for (int i = 0; i < 4; i++)
        for (int r = 0; r < 4; r++) rsum[i][r] = 0.f;
    }
    unsigned short* Cb = (unsigned short*)Cv;
    for (int i = 0; i < 4; i++) {
      int mg = m0 + wr * 64 + i * 16 + fq * 4;
      for (int j = 0; j < 4; j++) {
        int ng = n0 + wc * 64 + j * 16 + fr;
        for (int r = 0; r < 4; r++) {
          float v = acc[i][j][r];
          if (SCALE) v *= scale;
          if (BIASM == 1) v += bias[mg + r];
          else if (BIASM == 2) v += bias[ng];
          if (EXPSUM) { v = exp2f(v); rsum[i][r] += v; }
          if (ROWSCALE) v *= linv[i][r];
          Cb[z * sC + (long)(mg + r) * ldc + ng] = f2bf(v);
        }
      }
    }
    if (EXPSUM) {
      for (int i = 0; i < 4; i++)
        for (int r = 0; r < 4; r++) {
          float s = rsum[i][r];
          s += __shfl_xor(s, 1);
          s += __shfl_xor(s, 2);
          s += __shfl_xor(s, 4);
          s += __shfl_xor(s, 8);
          if (fr == 0)
            atomicAdd(&lsum[z * NPIX + m0 + wr * 64 + i * 16 + fq * 4 + r], s);
        }
    }
  }
}

extern "C" void kernel_launch(void* const* d_in, const int* in_sizes, int n_in,
                              void* d_out, int out_size, void* d_ws, size_t ws_size,
                              hipStream_t stream) {
  const float* x  = (const float*)d_in[0];
  const float* wq = (const float*)d_in[1];
  const float* bq = (const float*)d_in[2];
  const float* wk = (const float*)d_in[3];
  const float* bk = (const float*)d_in[4];
  const float* wv = (const float*)d_in[5];
  const float* bv = (const float*)d_in[6];
  const float* wp = (const float*)d_in[7];
  const float* bp = (const float*)d_in[8];

  char* ws = (char*)d_ws;
  const long SLAB = (long)NPIX * CCH;
  const long SLAB2 = (long)NPIX * 1024;
  const long SLABP = (long)NPIX * NPIX;

  float* stats = (float*)ws;
  float* bqk = (float*)(ws + (32l << 10));
  float* lsum = (float*)(ws + (64l << 10));
  unsigned short* wbf = (unsigned short*)(ws + (192l << 10));
  unsigned short* hnT = (unsigned short*)(ws + (192l << 10) + (1l << 21));
  unsigned short* QKt = hnT + 4 * SLAB;
  unsigned short* V   = QKt + 4 * SLAB2;
  unsigned short* Ot  = V + 4 * SLAB;
  unsigned short* S4  = Ot + 4 * SLAB;

  unsigned short* wv_bf = wbf + 2 * 262144;
  unsigned short* wp_bf = wbf + 3 * 262144;

  cast_weights_k<<<dim3(1024, 4, 1), 256, 0, stream>>>(wq, wk, wv, wp, wbf);
  bias_concat_k<<<dim3(4, 1, 1), 256, 0, stream>>>(bq, bk, bqk);
  zero_l_k<<<dim3(16, 1, 1), 256, 0, stream>>>(lsum);
  stats_k<<<dim3(NB * CCH, 1, 1), 256, 0, stream>>>(x, stats);
  norm_t_k<<<dim3(128, 16, 4), 256, 0, stream>>>(x, stats, hnT);

  // QKt[b][i][n] = hnT[b] . [wq;wk]^T + bqk
  gemm_bt_k<1, 0, 2, false, false, false, false><<<dim3(8, 32, 4), 256, 0, stream>>>(
      hnT, wbf, QKt, bqk, nullptr, nullptr, 512, 512, 512, 1024, SLAB, 0, SLAB2, 1.f);
  // V[b][o][j] = Wv . hnT[b]^T + bv
  gemm_bt_k<2, 0, 1, false, false, false, false><<<dim3(32, 4, 4), 256, 0, stream>>>(
      wv_bf, hnT, V, bv, nullptr, nullptr, 512, 512, 512, 4096, 0, SLAB, SLAB, 1.f);

  // scale = (1/sqrt(512)) * log2(e)
  const float isc2 = 0.06375871387551278f;
  // E = exp(Q.K^T/sqrt(C)) via 8-phase 256^2 kernel
  gemm8p_s_k<<<dim3(16, 16, 4), 512, 0, stream>>>(QKt, QKt + 512, S4, lsum, isc2);
  // Ot[b][i][c] = (E[b] . V[b]^T) / lsum[b][i]
  gemm_bt_k<1, 0, 0, false, false, false, true><<<dim3(4, 32, 4), 256, 0, stream>>>(
      S4, V, Ot, nullptr, nullptr, lsum, 4096, 4096, 4096, 512, SLABP, SLAB, SLAB, 1.f);
  // out[b][o][i] = x + Wp . Ot[b]^T + bp
  gemm_bt_k<2, 1, 1, true, false, false, false><<<dim3(32, 4, 4), 256, 0, stream>>>(
      wp_bf, Ot, d_out, bp, x, nullptr, 512, 512, 512, 4096, 0, SLAB, SLAB, 1.f);
}